// Round 2
// baseline (15879.776 us; speedup 1.0000x reference)
//
#include <hip/hip_runtime.h>

typedef _Float16 f16;
typedef _Float16 f16x8 __attribute__((ext_vector_type(8)));
typedef float f32x4 __attribute__((ext_vector_type(4)));

#define AS1 __attribute__((address_space(1)))
#define AS3 __attribute__((address_space(3)))

__device__ __forceinline__ void gload_lds16(const void* g, void* l) {
  __builtin_amdgcn_global_load_lds((const AS1 void*)g, (AS3 void*)l, 16, 0, 0);
}

// ---------------- conversion: fp32 -> fp16, 8 elems/thread ----------------
__global__ __launch_bounds__(256) void conv_f32_f16(const float* __restrict__ in,
                                                    f16* __restrict__ out, int n8) {
  int i = blockIdx.x * 256 + threadIdx.x;
  if (i >= n8) return;
  const float4* in4 = (const float4*)in;
  float4 a = in4[i * 2], b = in4[i * 2 + 1];
  f16x8 o = {(f16)a.x, (f16)a.y, (f16)a.z, (f16)a.w,
             (f16)b.x, (f16)b.y, (f16)b.z, (f16)b.w};
  *(f16x8*)(out + (size_t)i * 8) = o;
}

// ---------------- transpose+pack Wx gate g: [512,1024] -> rows g*1024+u of [4096,512] fp16
__global__ __launch_bounds__(256) void transp_wx(const float* __restrict__ src,
                                                 f16* __restrict__ dst, int gbase) {
  __shared__ float tile[32][33];
  const int tx = threadIdx.x, ty = threadIdx.y;
  const int c0 = blockIdx.x * 32, r0 = blockIdx.y * 32;
#pragma unroll
  for (int i = 0; i < 4; ++i)
    tile[ty + i * 8][tx] = src[(size_t)(r0 + ty + i * 8) * 1024 + c0 + tx];
  __syncthreads();
#pragma unroll
  for (int i = 0; i < 4; ++i) {
    int c = c0 + ty + i * 8;
    dst[(size_t)(gbase + c) * 512 + r0 + tx] = (f16)tile[tx][ty + i * 8];
  }
}

// ---------------- transpose+pack Wh gate g: [1024,1024] -> whP[(u>>4)*64 + g*16 + (u&15)][k]
__global__ __launch_bounds__(256) void transp_wh(const float* __restrict__ src,
                                                 f16* __restrict__ dst, int g) {
  __shared__ float tile[32][33];
  const int tx = threadIdx.x, ty = threadIdx.y;
  const int c0 = blockIdx.x * 32, r0 = blockIdx.y * 32;
#pragma unroll
  for (int i = 0; i < 4; ++i)
    tile[ty + i * 8][tx] = src[(size_t)(r0 + ty + i * 8) * 1024 + c0 + tx];
  __syncthreads();
#pragma unroll
  for (int i = 0; i < 4; ++i) {
    int uu = c0 + ty + i * 8;
    int drow = (uu >> 4) * 64 + g * 16 + (uu & 15);
    dst[(size_t)drow * 1024 + r0 + tx] = (f16)tile[tx][ty + i * 8];
  }
}

// ---------------- bias concat [g,i,f,o] ----------------
__global__ __launch_bounds__(256) void pack_bias(const float* __restrict__ bg,
                                                 const float* __restrict__ bi,
                                                 const float* __restrict__ bf,
                                                 const float* __restrict__ bo,
                                                 float* __restrict__ bc) {
  int n = blockIdx.x * 256 + threadIdx.x;
  int i = n & 1023;
  float v;
  if (n < 1024) v = bg[i];
  else if (n < 2048) v = bi[i];
  else if (n < 3072) v = bf[i];
  else v = bo[i];
  bc[n] = v;
}

// ---------------- x_proj GEMM: [32768,512]f16 x [512,4096](B^T layout) + bias -> f16 ----------------
__global__ __launch_bounds__(256) void gemm_xproj(const f16* __restrict__ A,
                                                  const f16* __restrict__ Bt,
                                                  const float* __restrict__ bias,
                                                  f16* __restrict__ C) {
  __shared__ f16 As[128 * 64];
  __shared__ f16 Bs[128 * 64];
  const int tid = threadIdx.x;
  const int l = tid & 63, wv = tid >> 6, lq = l >> 4, lr = l & 15;
  const int m0 = blockIdx.x * 128, n0 = blockIdx.y * 128;
  const int wrow = (wv >> 1) * 64, wcol = (wv & 1) * 64;
  f32x4 acc[4][4] = {};
  const int rA = tid >> 3, cA = (tid & 7) * 8;
  for (int kk = 0; kk < 8; ++kk) {
#pragma unroll
    for (int i = 0; i < 4; ++i) {
      gload_lds16(A + (size_t)(m0 + rA + i * 32) * 512 + kk * 64 + cA,
                  (char*)As + wv * 1024 + i * 4096);
      gload_lds16(Bt + (size_t)(n0 + rA + i * 32) * 512 + kk * 64 + cA,
                  (char*)Bs + wv * 1024 + i * 4096);
    }
    __syncthreads();
#pragma unroll
    for (int ks = 0; ks < 2; ++ks) {
      f16x8 a[4], b[4];
#pragma unroll
      for (int mt = 0; mt < 4; ++mt)
        a[mt] = *(const f16x8*)(As + (wrow + mt * 16 + lr) * 64 + ks * 32 + lq * 8);
#pragma unroll
      for (int nt = 0; nt < 4; ++nt)
        b[nt] = *(const f16x8*)(Bs + (wcol + nt * 16 + lr) * 64 + ks * 32 + lq * 8);
#pragma unroll
      for (int mt = 0; mt < 4; ++mt)
#pragma unroll
        for (int nt = 0; nt < 4; ++nt)
          acc[mt][nt] = __builtin_amdgcn_mfma_f32_16x16x32_f16(a[mt], b[nt], acc[mt][nt], 0, 0, 0);
    }
    __syncthreads();
  }
  float bb[4];
#pragma unroll
  for (int nt = 0; nt < 4; ++nt) bb[nt] = bias[n0 + wcol + nt * 16 + lr];
#pragma unroll
  for (int mt = 0; mt < 4; ++mt)
#pragma unroll
    for (int nt = 0; nt < 4; ++nt)
#pragma unroll
      for (int j = 0; j < 4; ++j) {
        int row = m0 + wrow + mt * 16 + lq * 4 + j;
        int col = n0 + wcol + nt * 16 + lr;
        C[(size_t)row * 4096 + col] = (f16)(acc[mt][nt][j] + bb[nt]);
      }
}

// ---------------- persistent LSTM recurrence ----------------
// 64 WGs x 1024 thr, 1 WG/CU. WG wg owns hidden units [16wg,16wg+16) -> 64 Wh cols LDS-resident.
// h exchange entirely via relaxed agent-scope (sc1, IF$-coherent) atomics: no L2 wbl2/inv fences.
// LDS: [0,128K) Wh (swizzled, col-major); [128K,144K) z-tile f32[64][64].
__global__ __launch_bounds__(1024) void lstm_rec(const f16* __restrict__ whP,
                                                 const f16* __restrict__ xp,
                                                 f16* __restrict__ hbuf,
                                                 float* __restrict__ out,
                                                 unsigned int* __restrict__ flags) {
  extern __shared__ char smem[];
  const int tid = threadIdx.x, wg = blockIdx.x;
  const int l = tid & 63, wv = tid >> 6, lq = l >> 4, lr = l & 15;
  const int rg = wv >> 2, cg = wv & 3;     // wave -> (row-grp of 16 batches, gate-col-grp)
  const int b = tid >> 4, u = tid & 15;    // gate-phase mapping
  // load Wh slice to LDS, XOR-swizzled, column-major (col c: gate=c>>4, unit=wg*16+(c&15))
  {
    const char* src = (const char*)(whP + (size_t)wg * 65536);
#pragma unroll
    for (int i = 0; i < 8; ++i) {
      int lin = (tid + i * 1024) * 16;
      int c = lin >> 11;
      uint4 v = *(const uint4*)(src + lin);
      *(uint4*)(smem + (lin ^ ((c & 7) << 4))) = v;
    }
  }
  float* zt = (float*)(smem + 131072);
  float c_state = 0.f;
  const int arow = rg * 16 + lr;           // batch row this lane's A-fragment covers
  const int bcol = cg * 16 + lr;           // Wh column this lane's B-fragment covers
  float xg[4];
  {
    const f16* xrow = xp + (size_t)b * 4096 + wg * 16 + u;  // t = 0
#pragma unroll
    for (int g = 0; g < 4; ++g) xg[g] = (float)xrow[g * 1024];
  }
  __syncthreads();
  for (int t = 0; t < 512; ++t) {
    const char* hsrc = (const char*)hbuf + (t & 1) * 131072;
    f32x4 acc = {0.f, 0.f, 0.f, 0.f};
#pragma unroll
    for (int kk = 0; kk < 16; ++kk) {
#pragma unroll
      for (int ks = 0; ks < 2; ++ks) {
        const unsigned long long* ap =
            (const unsigned long long*)(hsrc + arow * 2048 + kk * 128 + ks * 64 + lq * 16);
        unsigned long long a0 = __hip_atomic_load(ap, __ATOMIC_RELAXED, __HIP_MEMORY_SCOPE_AGENT);
        unsigned long long a1 = __hip_atomic_load(ap + 1, __ATOMIC_RELAXED, __HIP_MEMORY_SCOPE_AGENT);
        union { unsigned long long q[2]; f16x8 v; } au;
        au.q[0] = a0; au.q[1] = a1;
        f16x8 bv = *(const f16x8*)(smem +
            ((bcol * 2048 + kk * 128 + ks * 64 + lq * 16) ^ ((bcol & 7) << 4)));
        acc = __builtin_amdgcn_mfma_f32_16x16x32_f16(au.v, bv, acc, 0, 0, 0);
      }
    }
    // z exchange via LDS (4 gate-waves -> per-thread gate set)
#pragma unroll
    for (int j = 0; j < 4; ++j)
      zt[(rg * 16 + lq * 4 + j) * 64 + cg * 16 + lr] = acc[j];
    __syncthreads();
    float z0 = zt[b * 64 + u] + xg[0];
    float z1 = zt[b * 64 + 16 + u] + xg[1];
    float z2 = zt[b * 64 + 32 + u] + xg[2];
    float z3 = zt[b * 64 + 48 + u] + xg[3];
    float gv = tanhf(z0);
    float iv = 1.f / (1.f + __expf(-z1));
    float fv = 1.f / (1.f + __expf(-z2));
    float ov = 1.f / (1.f + __expf(-z3));
    c_state = gv * iv + c_state * fv;
    float hv = tanhf(c_state) * ov;
    // h store: pack 2 f16 per u32, relaxed agent-scope (sc1 -> IF$)
    unsigned short hu = __builtin_bit_cast(unsigned short, (f16)hv);
    unsigned other = (unsigned)__shfl_xor((int)(unsigned)hu, 1, 64);
    f16* hdst = hbuf + ((t + 1) & 1) * 65536;
    if (!(u & 1))
      __hip_atomic_store((unsigned*)(hdst + b * 1024 + wg * 16 + u),
                         ((unsigned)hu) | (other << 16),
                         __ATOMIC_RELAXED, __HIP_MEMORY_SCOPE_AGENT);
    asm volatile("s_waitcnt vmcnt(0)" ::: "memory");  // h stores acked at coherence point
    __syncthreads();
    if (tid == 0)
      __hip_atomic_store(&flags[wg], (unsigned)(t + 1), __ATOMIC_RELAXED, __HIP_MEMORY_SCOPE_AGENT);
    // off the critical path: output store + next-step xg prefetch
    const int hcol = wg * 16 + u;
    out[((size_t)t * 64 + b) * 1024 + hcol] = hv;
    if (t == 511) {
      out[(size_t)33554432 + b * 1024 + hcol] = hv;
    } else {
      const f16* xrow = xp + ((size_t)(t + 1) * 64 + b) * 4096 + wg * 16 + u;
#pragma unroll
      for (int g = 0; g < 4; ++g) xg[g] = (float)xrow[g * 1024];
    }
    if (tid < 64)
      while (__hip_atomic_load(&flags[tid], __ATOMIC_RELAXED, __HIP_MEMORY_SCOPE_AGENT) <
             (unsigned)(t + 1))
        __builtin_amdgcn_s_sleep(1);
    __syncthreads();
    asm volatile("" ::: "memory");
  }
}

extern "C" void kernel_launch(void* const* d_in, const int* in_sizes, int n_in,
                              void* d_out, int out_size, void* d_ws, size_t ws_size,
                              hipStream_t stream) {
  const float* embeds = (const float*)d_in[0];
  const float* W_fx = (const float*)d_in[1];
  const float* W_fh = (const float*)d_in[2];
  const float* b_f  = (const float*)d_in[3];
  const float* W_ix = (const float*)d_in[4];
  const float* W_ih = (const float*)d_in[5];
  const float* b_i  = (const float*)d_in[6];
  const float* W_gx = (const float*)d_in[7];
  const float* W_gh = (const float*)d_in[8];
  const float* b_g  = (const float*)d_in[9];
  const float* W_ox = (const float*)d_in[10];
  const float* W_oh = (const float*)d_in[11];
  const float* b_o  = (const float*)d_in[12];

  char* ws = (char*)d_ws;
  f16*   xproj = (f16*)(ws + 0);              // 268435456 B
  f16*   embF  = (f16*)(ws + 268435456);      // 33554432 B
  f16*   wxT   = (f16*)(ws + 301989888);      // 4194304 B
  f16*   whP   = (f16*)(ws + 306184192);      // 8388608 B
  float* bcat  = (float*)(ws + 314572800);    // 16384 B
  f16*   hbuf  = (f16*)(ws + 314589184);      // 262144 B
  unsigned int* flags = (unsigned int*)(ws + 314851328);  // 256 B
  if (ws_size < 314851584ull) return;

  hipMemsetAsync(hbuf, 0, 262144 + 256, stream);  // h0 = 0 (both buffers) + barrier flags

  conv_f32_f16<<<8192, 256, 0, stream>>>(embeds, embF, 2097152);
  const float* wxs[4] = {W_gx, W_ix, W_fx, W_ox};
  const float* whs[4] = {W_gh, W_ih, W_fh, W_oh};
  for (int g = 0; g < 4; ++g) {
    transp_wx<<<dim3(32, 16), dim3(32, 8), 0, stream>>>(wxs[g], wxT, g * 1024);
    transp_wh<<<dim3(32, 32), dim3(32, 8), 0, stream>>>(whs[g], whP, g);
  }
  pack_bias<<<16, 256, 0, stream>>>(b_g, b_i, b_f, b_o, bcat);
  gemm_xproj<<<dim3(256, 32), 256, 0, stream>>>(embF, wxT, bcat, xproj);

  hipFuncSetAttribute((const void*)lstm_rec, hipFuncAttributeMaxDynamicSharedMemorySize, 147456);
  lstm_rec<<<64, 1024, 147456, stream>>>(whP, xproj, hbuf, (float*)d_out, flags);
}

// Round 3
// 5829.899 us; speedup vs baseline: 2.7239x; 2.7239x over previous
//
#include <hip/hip_runtime.h>

typedef _Float16 f16;
typedef _Float16 f16x8 __attribute__((ext_vector_type(8)));
typedef float f32x4 __attribute__((ext_vector_type(4)));

#define AS1 __attribute__((address_space(1)))
#define AS3 __attribute__((address_space(3)))

__device__ __forceinline__ void gload_lds16(const void* g, void* l) {
  __builtin_amdgcn_global_load_lds((const AS1 void*)g, (AS3 void*)l, 16, 0, 0);
}

// ---------------- conversion: fp32 -> fp16, 8 elems/thread ----------------
__global__ __launch_bounds__(256) void conv_f32_f16(const float* __restrict__ in,
                                                    f16* __restrict__ out, int n8) {
  int i = blockIdx.x * 256 + threadIdx.x;
  if (i >= n8) return;
  const float4* in4 = (const float4*)in;
  float4 a = in4[i * 2], b = in4[i * 2 + 1];
  f16x8 o = {(f16)a.x, (f16)a.y, (f16)a.z, (f16)a.w,
             (f16)b.x, (f16)b.y, (f16)b.z, (f16)b.w};
  *(f16x8*)(out + (size_t)i * 8) = o;
}

// ---------------- transpose+pack Wx gate g: [512,1024] -> rows g*1024+u of [4096,512] fp16
__global__ __launch_bounds__(256) void transp_wx(const float* __restrict__ src,
                                                 f16* __restrict__ dst, int gbase) {
  __shared__ float tile[32][33];
  const int tx = threadIdx.x, ty = threadIdx.y;
  const int c0 = blockIdx.x * 32, r0 = blockIdx.y * 32;
#pragma unroll
  for (int i = 0; i < 4; ++i)
    tile[ty + i * 8][tx] = src[(size_t)(r0 + ty + i * 8) * 1024 + c0 + tx];
  __syncthreads();
#pragma unroll
  for (int i = 0; i < 4; ++i) {
    int c = c0 + ty + i * 8;
    dst[(size_t)(gbase + c) * 512 + r0 + tx] = (f16)tile[tx][ty + i * 8];
  }
}

// ---------------- transpose+pack Wh gate g: [1024,1024] -> whP[(u>>4)*64 + g*16 + (u&15)][k]
__global__ __launch_bounds__(256) void transp_wh(const float* __restrict__ src,
                                                 f16* __restrict__ dst, int g) {
  __shared__ float tile[32][33];
  const int tx = threadIdx.x, ty = threadIdx.y;
  const int c0 = blockIdx.x * 32, r0 = blockIdx.y * 32;
#pragma unroll
  for (int i = 0; i < 4; ++i)
    tile[ty + i * 8][tx] = src[(size_t)(r0 + ty + i * 8) * 1024 + c0 + tx];
  __syncthreads();
#pragma unroll
  for (int i = 0; i < 4; ++i) {
    int uu = c0 + ty + i * 8;
    int drow = (uu >> 4) * 64 + g * 16 + (uu & 15);
    dst[(size_t)drow * 1024 + r0 + tx] = (f16)tile[tx][ty + i * 8];
  }
}

// ---------------- bias concat [g,i,f,o] ----------------
__global__ __launch_bounds__(256) void pack_bias(const float* __restrict__ bg,
                                                 const float* __restrict__ bi,
                                                 const float* __restrict__ bf,
                                                 const float* __restrict__ bo,
                                                 float* __restrict__ bc) {
  int n = blockIdx.x * 256 + threadIdx.x;
  int i = n & 1023;
  float v;
  if (n < 1024) v = bg[i];
  else if (n < 2048) v = bi[i];
  else if (n < 3072) v = bf[i];
  else v = bo[i];
  bc[n] = v;
}

// ---------------- x_proj GEMM: [32768,512]f16 x [512,4096](B^T layout) + bias -> f16 ----------------
__global__ __launch_bounds__(256) void gemm_xproj(const f16* __restrict__ A,
                                                  const f16* __restrict__ Bt,
                                                  const float* __restrict__ bias,
                                                  f16* __restrict__ C) {
  __shared__ f16 As[128 * 64];
  __shared__ f16 Bs[128 * 64];
  const int tid = threadIdx.x;
  const int l = tid & 63, wv = tid >> 6, lq = l >> 4, lr = l & 15;
  const int m0 = blockIdx.x * 128, n0 = blockIdx.y * 128;
  const int wrow = (wv >> 1) * 64, wcol = (wv & 1) * 64;
  f32x4 acc[4][4] = {};
  const int rA = tid >> 3, cA = (tid & 7) * 8;
  for (int kk = 0; kk < 8; ++kk) {
#pragma unroll
    for (int i = 0; i < 4; ++i) {
      gload_lds16(A + (size_t)(m0 + rA + i * 32) * 512 + kk * 64 + cA,
                  (char*)As + wv * 1024 + i * 4096);
      gload_lds16(Bt + (size_t)(n0 + rA + i * 32) * 512 + kk * 64 + cA,
                  (char*)Bs + wv * 1024 + i * 4096);
    }
    __syncthreads();
#pragma unroll
    for (int ks = 0; ks < 2; ++ks) {
      f16x8 a[4], b[4];
#pragma unroll
      for (int mt = 0; mt < 4; ++mt)
        a[mt] = *(const f16x8*)(As + (wrow + mt * 16 + lr) * 64 + ks * 32 + lq * 8);
#pragma unroll
      for (int nt = 0; nt < 4; ++nt)
        b[nt] = *(const f16x8*)(Bs + (wcol + nt * 16 + lr) * 64 + ks * 32 + lq * 8);
#pragma unroll
      for (int mt = 0; mt < 4; ++mt)
#pragma unroll
        for (int nt = 0; nt < 4; ++nt)
          acc[mt][nt] = __builtin_amdgcn_mfma_f32_16x16x32_f16(a[mt], b[nt], acc[mt][nt], 0, 0, 0);
    }
    __syncthreads();
  }
  float bb[4];
#pragma unroll
  for (int nt = 0; nt < 4; ++nt) bb[nt] = bias[n0 + wcol + nt * 16 + lr];
#pragma unroll
  for (int mt = 0; mt < 4; ++mt)
#pragma unroll
    for (int nt = 0; nt < 4; ++nt)
#pragma unroll
      for (int j = 0; j < 4; ++j) {
        int row = m0 + wrow + mt * 16 + lq * 4 + j;
        int col = n0 + wcol + nt * 16 + lr;
        C[(size_t)row * 4096 + col] = (f16)(acc[mt][nt][j] + bb[nt]);
      }
}

// ---------------- persistent LSTM recurrence ----------------
// 64 WGs x 1024 thr (16 waves), 1 WG/CU. WG wg owns hidden units [16wg,16wg+16) -> 64 Wh cols LDS-resident.
// Wave (rg,ks) = (wv&3, wv>>2): rows rg*16..+16, k in [ks*256, ks*256+256), all 64 cols.
// A (h) loads: batched relaxed sc1 (IF$-coherent), 16 in flight, each h byte read ONCE per CU.
// k-split partial z reduced via 4 in-place LDS add phases into Z[64][66] f32 (padded).
// LDS: [0,128K) Wh swizzled col-major; [128K, 128K+16.5K) Z.
__global__ __launch_bounds__(1024) void lstm_rec(const f16* __restrict__ whP,
                                                 const f16* __restrict__ xp,
                                                 f16* __restrict__ hbuf,
                                                 float* __restrict__ out,
                                                 unsigned int* __restrict__ flags) {
  extern __shared__ char smem[];
  const int tid = threadIdx.x, wg = blockIdx.x;
  const int l = tid & 63, wv = tid >> 6, lq = l >> 4, lr = l & 15;
  const int rg = wv & 3, ks = wv >> 2;     // row-group, k-split
  const int b = tid >> 4, u = tid & 15;    // gate-phase mapping
  // load Wh slice to LDS, XOR-swizzled, column-major (col c: gate=c>>4, unit=wg*16+(c&15))
  {
    const char* src = (const char*)(whP + (size_t)wg * 65536);
#pragma unroll
    for (int i = 0; i < 8; ++i) {
      int lin = (tid + i * 1024) * 16;
      int c = lin >> 11;
      uint4 v = *(const uint4*)(src + lin);
      *(uint4*)(smem + (lin ^ ((c & 7) << 4))) = v;
    }
  }
  float* Z = (float*)(smem + 131072);      // [64][66] f32
  float c_state = 0.f;
  const int arow = rg * 16 + lr;
  const int kbase = ks * 512 + lq * 16;    // byte offset of this lane's k-slice
  float xg[4];
  {
    const f16* xrow = xp + (size_t)b * 4096 + wg * 16 + u;  // t = 0
#pragma unroll
    for (int g = 0; g < 4; ++g) xg[g] = (float)xrow[g * 1024];
  }
  __syncthreads();
  for (int t = 0; t < 512; ++t) {
    // ---- batched A-fragment loads (one IF$ latency exposure, 16 in flight) ----
    const char* hsrc = (const char*)hbuf + (t & 1) * 131072 + arow * 2048 + kbase;
    unsigned long long pre[16];
#pragma unroll
    for (int kk = 0; kk < 8; ++kk) {
      pre[kk * 2] = __hip_atomic_load((const unsigned long long*)(hsrc + kk * 64),
                                      __ATOMIC_RELAXED, __HIP_MEMORY_SCOPE_AGENT);
      pre[kk * 2 + 1] = __hip_atomic_load((const unsigned long long*)(hsrc + kk * 64 + 8),
                                          __ATOMIC_RELAXED, __HIP_MEMORY_SCOPE_AGENT);
    }
    // ---- 32 MFMAs: 16 rows x 64 cols x 256 k (partial) ----
    f32x4 acc[4] = {{0.f, 0.f, 0.f, 0.f}, {0.f, 0.f, 0.f, 0.f},
                    {0.f, 0.f, 0.f, 0.f}, {0.f, 0.f, 0.f, 0.f}};
#pragma unroll
    for (int kk = 0; kk < 8; ++kk) {
      union { unsigned long long q[2]; f16x8 v; } au;
      au.q[0] = pre[kk * 2]; au.q[1] = pre[kk * 2 + 1];
#pragma unroll
      for (int cc = 0; cc < 4; ++cc) {
        int col = cc * 16 + lr;
        f16x8 bv = *(const f16x8*)(smem + ((col * 2048 + kbase + kk * 64) ^ ((col & 7) << 4)));
        acc[cc] = __builtin_amdgcn_mfma_f32_16x16x32_f16(au.v, bv, acc[cc], 0, 0, 0);
      }
    }
    // ---- 4-phase in-place k-split reduction into Z ----
#define ZP(cc, j) (Z + (rg * 16 + lq * 4 + (j)) * 66 + (cc) * 16 + lr)
    if (ks == 3) {
#pragma unroll
      for (int cc = 0; cc < 4; ++cc)
#pragma unroll
        for (int j = 0; j < 4; ++j) *ZP(cc, j) = acc[cc][j];
    }
    __syncthreads();
    if (ks == 2) {
#pragma unroll
      for (int cc = 0; cc < 4; ++cc)
#pragma unroll
        for (int j = 0; j < 4; ++j) *ZP(cc, j) += acc[cc][j];
    }
    __syncthreads();
    if (ks == 1) {
#pragma unroll
      for (int cc = 0; cc < 4; ++cc)
#pragma unroll
        for (int j = 0; j < 4; ++j) *ZP(cc, j) += acc[cc][j];
    }
    __syncthreads();
    if (ks == 0) {
#pragma unroll
      for (int cc = 0; cc < 4; ++cc)
#pragma unroll
        for (int j = 0; j < 4; ++j) *ZP(cc, j) += acc[cc][j];
    }
    __syncthreads();
#undef ZP
    // ---- gates ----
    float z0 = Z[b * 66 + u] + xg[0];
    float z1 = Z[b * 66 + 16 + u] + xg[1];
    float z2 = Z[b * 66 + 32 + u] + xg[2];
    float z3 = Z[b * 66 + 48 + u] + xg[3];
    float gv = tanhf(z0);
    float iv = 1.f / (1.f + __expf(-z1));
    float fv = 1.f / (1.f + __expf(-z2));
    float ov = 1.f / (1.f + __expf(-z3));
    c_state = gv * iv + c_state * fv;
    float hv = tanhf(c_state) * ov;
    // ---- h store: pack 2 f16 per u32, relaxed agent-scope (sc1 -> IF$) ----
    unsigned short hu = __builtin_bit_cast(unsigned short, (f16)hv);
    unsigned other = (unsigned)__shfl_xor((int)(unsigned)hu, 1, 64);
    f16* hdst = hbuf + ((t + 1) & 1) * 65536;
    if (!(u & 1))
      __hip_atomic_store((unsigned*)(hdst + b * 1024 + wg * 16 + u),
                         ((unsigned)hu) | (other << 16),
                         __ATOMIC_RELAXED, __HIP_MEMORY_SCOPE_AGENT);
    asm volatile("s_waitcnt vmcnt(0)" ::: "memory");  // h stores acked at coherence point
    __syncthreads();
    if (tid == 0)
      __hip_atomic_store(&flags[wg], (unsigned)(t + 1), __ATOMIC_RELAXED, __HIP_MEMORY_SCOPE_AGENT);
    // off the critical path: output store + next-step xg prefetch
    const int hcol = wg * 16 + u;
    out[((size_t)t * 64 + b) * 1024 + hcol] = hv;
    if (t == 511) {
      out[(size_t)33554432 + b * 1024 + hcol] = hv;
    } else {
      const f16* xrow = xp + ((size_t)(t + 1) * 64 + b) * 4096 + wg * 16 + u;
#pragma unroll
      for (int g = 0; g < 4; ++g) xg[g] = (float)xrow[g * 1024];
    }
    if (tid < 64)
      while (__hip_atomic_load(&flags[tid], __ATOMIC_RELAXED, __HIP_MEMORY_SCOPE_AGENT) <
             (unsigned)(t + 1))
        __builtin_amdgcn_s_sleep(1);
    __syncthreads();
    asm volatile("" ::: "memory");
  }
}

extern "C" void kernel_launch(void* const* d_in, const int* in_sizes, int n_in,
                              void* d_out, int out_size, void* d_ws, size_t ws_size,
                              hipStream_t stream) {
  const float* embeds = (const float*)d_in[0];
  const float* W_fx = (const float*)d_in[1];
  const float* W_fh = (const float*)d_in[2];
  const float* b_f  = (const float*)d_in[3];
  const float* W_ix = (const float*)d_in[4];
  const float* W_ih = (const float*)d_in[5];
  const float* b_i  = (const float*)d_in[6];
  const float* W_gx = (const float*)d_in[7];
  const float* W_gh = (const float*)d_in[8];
  const float* b_g  = (const float*)d_in[9];
  const float* W_ox = (const float*)d_in[10];
  const float* W_oh = (const float*)d_in[11];
  const float* b_o  = (const float*)d_in[12];

  char* ws = (char*)d_ws;
  f16*   xproj = (f16*)(ws + 0);              // 268435456 B
  f16*   embF  = (f16*)(ws + 268435456);      // 33554432 B
  f16*   wxT   = (f16*)(ws + 301989888);      // 4194304 B
  f16*   whP   = (f16*)(ws + 306184192);      // 8388608 B
  float* bcat  = (float*)(ws + 314572800);    // 16384 B
  f16*   hbuf  = (f16*)(ws + 314589184);      // 262144 B
  unsigned int* flags = (unsigned int*)(ws + 314851328);  // 256 B
  if (ws_size < 314851584ull) return;

  hipMemsetAsync(hbuf, 0, 262144 + 256, stream);  // h0 = 0 (both buffers) + barrier flags

  conv_f32_f16<<<8192, 256, 0, stream>>>(embeds, embF, 2097152);
  const float* wxs[4] = {W_gx, W_ix, W_fx, W_ox};
  const float* whs[4] = {W_gh, W_ih, W_fh, W_oh};
  for (int g = 0; g < 4; ++g) {
    transp_wx<<<dim3(32, 16), dim3(32, 8), 0, stream>>>(wxs[g], wxT, g * 1024);
    transp_wh<<<dim3(32, 32), dim3(32, 8), 0, stream>>>(whs[g], whP, g);
  }
  pack_bias<<<16, 256, 0, stream>>>(b_g, b_i, b_f, b_o, bcat);
  gemm_xproj<<<dim3(256, 32), 256, 0, stream>>>(embF, wxT, bcat, xproj);

  hipFuncSetAttribute((const void*)lstm_rec, hipFuncAttributeMaxDynamicSharedMemorySize, 147968);
  lstm_rec<<<64, 1024, 147968, stream>>>(whP, xproj, hbuf, (float*)d_out, flags);
}